// Round 9
// baseline (230.090 us; speedup 1.0000x reference)
//
#include <hip/hip_runtime.h>
#include <math.h>

// Problem constants: IN_DIM=128, HEADS=8, HEAD_DIM=16, HEADS*HEAD_DIM=128.
#define DIM 128
#define N_HEADS 8
#define HD 16
#define CAP 64   // bucket capacity (deg ~Poisson(16); P(>64)~3e-22)

// ROUND-9 ATTRIBUTION BUILD: exact round-2 components, 4 separate dispatches,
// so append / qkv / aggregate each get their own rocprof row. Round-8 fused
// append_qkv was 86us across three different append designs while all pipes
// sat idle -- the split between append-phase and qkv-phase (and ~60us of
// never-profiled time) could not be attributed inside one dispatch.

typedef __attribute__((ext_vector_type(8))) short bf16x8;   // MFMA A/B frag (4 VGPRs)
typedef __attribute__((ext_vector_type(4))) float f32x4;    // MFMA C/D frag

// ---------------------------------------------------------------------------
// bf16 helpers (RNE pack, cheap unpack)
// ---------------------------------------------------------------------------
__device__ __forceinline__ unsigned bf16pack2(float a, float b) {
    unsigned ua = __builtin_bit_cast(unsigned, a);
    unsigned ub = __builtin_bit_cast(unsigned, b);
    ua = (ua + 0x7FFFu + ((ua >> 16) & 1u)) >> 16;
    ub = (ub + 0x7FFFu + ((ub >> 16) & 1u)) >> 16;
    return ua | (ub << 16);
}
__device__ __forceinline__ float bf16lo(unsigned p) {
    return __builtin_bit_cast(float, p << 16);
}
__device__ __forceinline__ float bf16hi(unsigned p) {
    return __builtin_bit_cast(float, p & 0xFFFF0000u);
}

// ---------------------------------------------------------------------------
// Init: zero cnt (blocks [0,NB)) || convert W -> WT/bias384 (blocks >= NB).
// ---------------------------------------------------------------------------
__global__ __launch_bounds__(256)
void init_kernel(const float* __restrict__ WQ, const float* __restrict__ bQ,
                 const float* __restrict__ WK, const float* __restrict__ bK,
                 const float* __restrict__ WV, const float* __restrict__ bV,
                 unsigned short* __restrict__ WT, float* __restrict__ bias384,
                 int* __restrict__ cnt, int NB, int N)
{
    if ((int)blockIdx.x < NB) {
        int i = blockIdx.x * 256 + threadIdx.x;
        if (i < N) cnt[i] = 0;
    } else {
        int idx = ((int)blockIdx.x - NB) * 256 + threadIdx.x;   // 0..49151
        int c = idx >> 7, k = idx & 127;
        const float* W; const float* b; int col = c & 127;
        if (c < 128)      { W = WQ; b = bQ; }
        else if (c < 256) { W = WK; b = bK; }
        else              { W = WV; b = bV; }
        float v = W[k * DIM + col];
        WT[(size_t)c * DIM + k] = (unsigned short)(bf16pack2(v, 0.0f) & 0xFFFFu);
        if (k == 0) bias384[c] = b[col];
    }
}

// ---------------------------------------------------------------------------
// Append (exact round-2 structure, standalone): 4 edges/thread, int4 edge
// loads, 4 independent atomics in flight, ushort bucket entries (N < 65536).
// Standalone => VGPR ~24, no LDS => up to 32 waves/CU for latency hiding.
// THE key measurement this round: is this kernel ~10us or ~80us on its own?
// ---------------------------------------------------------------------------
__global__ __launch_bounds__(256)
void append_kernel(const int* __restrict__ src, const int* __restrict__ dst,
                   int* __restrict__ cnt, unsigned short* __restrict__ srcsF, int E)
{
    int t = (blockIdx.x * 256 + threadIdx.x) * 4;
    if (t + 3 < E) {
        int4 d4 = *(const int4*)(dst + t);
        int4 s4 = *(const int4*)(src + t);
        int sl0 = atomicAdd(&cnt[d4.x], 1);
        int sl1 = atomicAdd(&cnt[d4.y], 1);
        int sl2 = atomicAdd(&cnt[d4.z], 1);
        int sl3 = atomicAdd(&cnt[d4.w], 1);
        if (sl0 < CAP) srcsF[(size_t)d4.x * CAP + sl0] = (unsigned short)s4.x;
        if (sl1 < CAP) srcsF[(size_t)d4.y * CAP + sl1] = (unsigned short)s4.y;
        if (sl2 < CAP) srcsF[(size_t)d4.z * CAP + sl2] = (unsigned short)s4.z;
        if (sl3 < CAP) srcsF[(size_t)d4.w * CAP + sl3] = (unsigned short)s4.w;
    } else {
        for (int e = t; e < E; ++e) {
            int d    = dst[e];
            int slot = atomicAdd(&cnt[d], 1);
            if (slot < CAP) srcsF[(size_t)d * CAP + slot] = (unsigned short)src[e];
        }
    }
}

// ---------------------------------------------------------------------------
// QKV via bf16 MFMA 16x16x32 (exact round-2 structure, standalone).
// A = WT (m = output col), B = h tile (n = node).
// Qd layout (dwords; row n = 64 dwords = 256 B): dword j = Q dims 2j,2j+1.
// KV chunk layout (dwords; row n = 128 dwords = 512 B):
//   chunk c in [0,16): dwords [8c..8c+3] = K dims 8c..8c+7,
//                      dwords [8c+4..8c+7] = V dims 8c..8c+7.
// ---------------------------------------------------------------------------
__global__ __launch_bounds__(256)
void qkv_mfma_kernel(const float* __restrict__ h,
                     const unsigned short* __restrict__ WT,
                     const float* __restrict__ bias384,
                     unsigned* __restrict__ Qd, unsigned* __restrict__ KVd,
                     int N)
{
    __shared__ unsigned short hs[64 * 136];
    const int tid = threadIdx.x;
    const int n0  = blockIdx.x * 64;

    #pragma unroll
    for (int i = 0; i < 4; ++i) {
        int lin  = i * 256 + tid;          // 0..1023
        int node = lin >> 4;               // 0..63
        int k0   = (lin & 15) * 8;         // 0..120
        int gn   = n0 + node;
        float4 a0, a1;
        if (gn < N) {
            a0 = *(const float4*)(h + (size_t)gn * DIM + k0);
            a1 = *(const float4*)(h + (size_t)gn * DIM + k0 + 4);
        } else {
            a0 = make_float4(0.f, 0.f, 0.f, 0.f);
            a1 = a0;
        }
        uint4 p = make_uint4(bf16pack2(a0.x, a0.y), bf16pack2(a0.z, a0.w),
                             bf16pack2(a1.x, a1.y), bf16pack2(a1.z, a1.w));
        *(uint4*)(hs + node * 136 + k0) = p;
    }
    __syncthreads();

    const int wave   = tid >> 6;
    const int l      = tid & 63;
    const int lane16 = l & 15;
    const int quad   = l >> 4;
    const int wc0    = wave * 96;

    f32x4 acc[6][4];
    #pragma unroll
    for (int ct = 0; ct < 6; ++ct) {
        float4 bv = *(const float4*)(bias384 + wc0 + ct * 16 + quad * 4);
        #pragma unroll
        for (int rt = 0; rt < 4; ++rt)
            acc[ct][rt] = (f32x4){bv.x, bv.y, bv.z, bv.w};
    }

    #pragma unroll
    for (int ks = 0; ks < 4; ++ks) {
        bf16x8 a[6], b[4];
        #pragma unroll
        for (int ct = 0; ct < 6; ++ct)
            a[ct] = *(const bf16x8*)(WT + (size_t)(wc0 + ct * 16 + lane16) * DIM
                                         + ks * 32 + quad * 8);
        #pragma unroll
        for (int rt = 0; rt < 4; ++rt)
            b[rt] = *(const bf16x8*)(hs + (rt * 16 + lane16) * 136 + ks * 32 + quad * 8);
        #pragma unroll
        for (int ct = 0; ct < 6; ++ct)
            #pragma unroll
            for (int rt = 0; rt < 4; ++rt)
                acc[ct][rt] = __builtin_amdgcn_mfma_f32_16x16x32_bf16(
                    a[ct], b[rt], acc[ct][rt], 0, 0, 0);
    }

    #pragma unroll
    for (int ct = 0; ct < 6; ++ct) {
        const int col = wc0 + ct * 16 + quad * 4;   // multiple of 4
        #pragma unroll
        for (int rt = 0; rt < 4; ++rt) {
            int gn = n0 + rt * 16 + lane16;
            if (gn >= N) continue;
            f32x4 v = acc[ct][rt];
            uint2 pr = make_uint2(bf16pack2(v[0], v[1]), bf16pack2(v[2], v[3]));
            if (col < 128) {
                *(uint2*)(Qd + (size_t)gn * 64 + (col >> 1)) = pr;
            } else if (col < 256) {
                int c = col - 128;
                *(uint2*)(KVd + (size_t)gn * 128 + ((c >> 3) * 8) + ((c & 4) >> 1)) = pr;
            } else {
                int c = col - 256;
                *(uint2*)(KVd + (size_t)gn * 128 + ((c >> 3) * 8) + 4 + ((c & 4) >> 1)) = pr;
            }
        }
    }
}

// ---------------------------------------------------------------------------
// Aggregate: EXACT round-2 v2 (measured 62us; best of 7 structures tried).
// Persistent grid-stride waves + cross-node meta prefetch. Wave = one dst
// node, 4 edge slots, 16 lanes/edge (c = l&15 -> dims c*8..c*8+7).
// ---------------------------------------------------------------------------
__device__ __forceinline__ void agg_chunk16(
    const unsigned* __restrict__ KVd, int eg, int deg, int slot, int c,
    const int* raw,
    float q0, float q1, float q2, float q3,
    float q4, float q5, float q6, float q7,
    float acc[8], float& zs)
{
    bool val[4];
    const uint4* p[4];
    #pragma unroll
    for (int j = 0; j < 4; ++j) {
        int ee = eg + j * 4 + slot;
        val[j] = ee < deg;
        int s  = val[j] ? raw[j] : 0;
        p[j]   = (const uint4*)(KVd + (size_t)s * 128 + c * 8);
    }
    uint4 K[4], V[4];
    #pragma unroll
    for (int j = 0; j < 4; ++j) { K[j] = p[j][0]; V[j] = p[j][1]; }

    float d[4];
    #pragma unroll
    for (int j = 0; j < 4; ++j)
        d[j] = bf16lo(K[j].x) * q0 + bf16hi(K[j].x) * q1
             + bf16lo(K[j].y) * q2 + bf16hi(K[j].y) * q3
             + bf16lo(K[j].z) * q4 + bf16hi(K[j].z) * q5
             + bf16lo(K[j].w) * q6 + bf16hi(K[j].w) * q7;
    #pragma unroll
    for (int j = 0; j < 4; ++j) d[j] += __shfl_xor(d[j], 1);

    #pragma unroll
    for (int j = 0; j < 4; ++j) {
        float pc = fminf(fmaxf(d[j] * 0.25f, -5.0f), 5.0f);
        float w  = val[j] ? __expf(pc) : 0.0f;
        zs += w;
        acc[0] += w * bf16lo(V[j].x); acc[1] += w * bf16hi(V[j].x);
        acc[2] += w * bf16lo(V[j].y); acc[3] += w * bf16hi(V[j].y);
        acc[4] += w * bf16lo(V[j].z); acc[5] += w * bf16hi(V[j].z);
        acc[6] += w * bf16lo(V[j].w); acc[7] += w * bf16hi(V[j].w);
    }
}

__global__ __launch_bounds__(256, 4)
void aggregate_kernel(const int* __restrict__ cnt,
                      const unsigned short* __restrict__ srcsF,
                      const unsigned* __restrict__ Qd, const unsigned* __restrict__ KVd,
                      float* __restrict__ out, int N)
{
    const int l      = threadIdx.x & 63;
    const int slot   = l >> 4;
    const int c      = l & 15;
    const int stride = gridDim.x * 4;

    int node = blockIdx.x * 4 + (threadIdx.x >> 6);
    if (node >= N) return;

    // prime the pipeline: current node's deg, Q row, first 32 bucket slots
    int   deg = cnt[node];
    uint4 qd  = *(const uint4*)(Qd + (size_t)node * 64 + c * 4);
    int   pb[8];
    {
        const unsigned short* b = srcsF + (size_t)node * CAP;
        #pragma unroll
        for (int j = 0; j < 8; ++j)
            pb[j] = b[((j >> 2) << 4) + ((j & 3) << 2) + slot];   // ee 0..31
    }

    for (;;) {
        const int  nnode   = node + stride;
        const bool hasNext = nnode < N;

        // ---- prefetch next node (independent loads, hide under compute) --
        int ndeg = 0; uint4 nqd = make_uint4(0u, 0u, 0u, 0u); int npb[8];
        #pragma unroll
        for (int j = 0; j < 8; ++j) npb[j] = 0;
        if (hasNext) {
            ndeg = cnt[nnode];
            nqd  = *(const uint4*)(Qd + (size_t)nnode * 64 + c * 4);
            const unsigned short* b = srcsF + (size_t)nnode * CAP;
            #pragma unroll
            for (int j = 0; j < 8; ++j)
                npb[j] = b[((j >> 2) << 4) + ((j & 3) << 2) + slot];
        }

        // ---- process current node ---------------------------------------
        int degc = deg > CAP ? CAP : deg;
        const float q0 = bf16lo(qd.x), q1 = bf16hi(qd.x);
        const float q2 = bf16lo(qd.y), q3 = bf16hi(qd.y);
        const float q4 = bf16lo(qd.z), q5 = bf16hi(qd.z);
        const float q6 = bf16lo(qd.w), q7 = bf16hi(qd.w);

        float acc[8] = {0.f, 0.f, 0.f, 0.f, 0.f, 0.f, 0.f, 0.f};
        float zs = 0.f;

        if (degc > 0)
            agg_chunk16(KVd, 0, degc, slot, c, pb,
                        q0, q1, q2, q3, q4, q5, q6, q7, acc, zs);
        if (degc > 16)
            agg_chunk16(KVd, 16, degc, slot, c, pb + 4,
                        q0, q1, q2, q3, q4, q5, q6, q7, acc, zs);
        for (int eg = 32; eg < degc; eg += 16) {       // rare tail (deg > 32)
            int raw[4];
            const unsigned short* b = srcsF + (size_t)node * CAP;
            #pragma unroll
            for (int j = 0; j < 4; ++j) {
                int ee = eg + j * 4 + slot;
                raw[j] = b[ee < degc ? ee : 0];
            }
            agg_chunk16(KVd, eg, degc, slot, c, raw,
                        q0, q1, q2, q3, q4, q5, q6, q7, acc, zs);
        }

        // ---- cross-slot reduce (slots live in lane bits 4-5) ------------
        #pragma unroll
        for (int j = 0; j < 8; ++j) {
            acc[j] += __shfl_xor(acc[j], 16);
            acc[j] += __shfl_xor(acc[j], 32);
        }
        zs += __shfl_xor(zs, 16);
        zs += __shfl_xor(zs, 32);

        if (slot == 0) {
            float inv = (zs > 0.0f) ? (1.0f / zs) : 0.0f;
            *(float4*)(out + (size_t)node * DIM + c * 8) =
                make_float4(acc[0] * inv, acc[1] * inv, acc[2] * inv, acc[3] * inv);
            *(float4*)(out + (size_t)node * DIM + c * 8 + 4) =
                make_float4(acc[4] * inv, acc[5] * inv, acc[6] * inv, acc[7] * inv);
        }

        if (!hasNext) break;
        node = nnode; deg = ndeg; qd = nqd;
        #pragma unroll
        for (int j = 0; j < 8; ++j) pb[j] = npb[j];
    }
}

// ---------------------------------------------------------------------------
extern "C" void kernel_launch(void* const* d_in, const int* in_sizes, int n_in,
                              void* d_out, int out_size, void* d_ws, size_t ws_size,
                              hipStream_t stream) {
    const float* h   = (const float*)d_in[0];
    const int*   src = (const int*)  d_in[1];
    const int*   dst = (const int*)  d_in[2];
    const float* WQ  = (const float*)d_in[3];
    const float* bQ  = (const float*)d_in[4];
    const float* WK  = (const float*)d_in[5];
    const float* bK  = (const float*)d_in[6];
    const float* WV  = (const float*)d_in[7];
    const float* bV  = (const float*)d_in[8];
    float* out = (float*)d_out;

    const int N  = in_sizes[0] / DIM;
    const int E  = in_sizes[1];
    const int NB = (N + 255) / 256;            // blocks to zero cnt
    const int EB = (E / 4 + 255) / 256;        // append blocks (4 edges/thread)
    const int QB = (N + 63) / 64;              // qkv blocks
    const int nConv = (384 * DIM) / 256;       // convert blocks

    // Workspace: Qd (12.8MB) | KVd (25.6MB) | WT (96KB) | bias384 | cnt (200KB)
    //            | srcsF (N*CAP*2 = 6.4MB)   -> ~45 MB total
    char* w = (char*)d_ws;
    unsigned*       Qd      = (unsigned*)w;        w += (size_t)N * 64  * sizeof(unsigned);
    unsigned*       KVd     = (unsigned*)w;        w += (size_t)N * 128 * sizeof(unsigned);
    unsigned short* WT      = (unsigned short*)w;  w += (size_t)384 * DIM * sizeof(unsigned short);
    float*          bias384 = (float*)w;           w += 384 * sizeof(float);
    int*            cnt     = (int*)w;             w += (size_t)N * sizeof(int);
    unsigned short* srcsF   = (unsigned short*)w;

    init_kernel<<<NB + nConv, 256, 0, stream>>>(WQ, bQ, WK, bK, WV, bV,
                                                WT, bias384, cnt, NB, N);
    append_kernel<<<EB, 256, 0, stream>>>(src, dst, cnt, srcsF, E);
    qkv_mfma_kernel<<<QB, 256, 0, stream>>>(h, WT, bias384, Qd, KVd, N);
    aggregate_kernel<<<2048, 256, 0, stream>>>(cnt, srcsF, Qd, KVd, out, N);
}

// Round 11
// 215.931 us; speedup vs baseline: 1.0656x; 1.0656x over previous
//
#include <hip/hip_runtime.h>
#include <math.h>

// Problem constants: IN_DIM=128, HEADS=8, HEAD_DIM=16, HEADS*HEAD_DIM=128.
#define DIM 128
#define N_HEADS 8
#define HD 16
#define CAP 64   // bucket capacity (deg ~Poisson(16); P(>64)~3e-22)

typedef __attribute__((ext_vector_type(8))) short bf16x8;   // MFMA A/B frag (4 VGPRs)
typedef __attribute__((ext_vector_type(4))) float f32x4;    // MFMA C/D frag
typedef __attribute__((ext_vector_type(4))) unsigned ui32x4;

// ---------------------------------------------------------------------------
// ROUND-11: init dispatch deleted.
//   * cnt zeroing -> hipMemsetAsync (DMA blit, graph-capturable -- the
//     harness's own reset() uses it; replaces a full kernel dispatch).
//   * WT/bias384 precompute -> qkv packs fragments directly from f32 W
//     (192KB, L2-resident; 8 strided dword loads + 4 packs per fragment,
//     ~+3-5us on qkv -- less than the ~13us the init dispatch cost).
// Ledger: fixed overhead ~47us + ~9us/dispatch (R1vsR2, R8vsR9 replicated);
// R8 = init 4 + aq 86 + agg 65 + 2x9 + 47 = 220. This build: 2 kernels + 1
// memset -> predict 208-214.
// Components otherwise proven-best: fused aq append-first (R5, 83.4us),
// aggregate verbatim R2 (61.4-62.0us, best of 10 structures).
// ---------------------------------------------------------------------------

__device__ __forceinline__ unsigned bf16pack2(float a, float b) {
    unsigned ua = __builtin_bit_cast(unsigned, a);
    unsigned ub = __builtin_bit_cast(unsigned, b);
    ua = (ua + 0x7FFFu + ((ua >> 16) & 1u)) >> 16;
    ub = (ub + 0x7FFFu + ((ub >> 16) & 1u)) >> 16;
    return ua | (ub << 16);
}
__device__ __forceinline__ float bf16lo(unsigned p) {
    return __builtin_bit_cast(float, p << 16);
}
__device__ __forceinline__ float bf16hi(unsigned p) {
    return __builtin_bit_cast(float, p & 0xFFFF0000u);
}

// ---------------------------------------------------------------------------
// Fused append + qkv. Append blocks FIRST (R5 order, 83.4us measured).
// append: 4 edges/thread, int4 edge loads, ushort bucket entries (N < 65536).
// qkv: A-fragments packed on the fly from f32 W (no WT): for output col c,
//   a[j] = bf16(W_m[(ks*32+quad*8+j)*128 + c%128]) -- 8 dword loads, stride
//   512B, 16 consecutive lanes = 64B segments, all L2-hits after warmup.
// Qd layout (dwords; row n = 64 dwords = 256 B): dword j = Q dims 2j,2j+1.
// KV chunk layout (dwords; row n = 128 dwords = 512 B):
//   chunk c in [0,16): dwords [8c..8c+3] = K dims 8c..8c+7,
//                      dwords [8c+4..8c+7] = V dims 8c..8c+7.
// ---------------------------------------------------------------------------
__global__ __launch_bounds__(256)
void append_qkv_kernel(const int* __restrict__ src, const int* __restrict__ dst,
                       int* __restrict__ cnt, unsigned short* __restrict__ srcsF,
                       int E, int AB,
                       const float* __restrict__ h,
                       const float* __restrict__ WQ, const float* __restrict__ bQ,
                       const float* __restrict__ WK, const float* __restrict__ bK,
                       const float* __restrict__ WV, const float* __restrict__ bV,
                       unsigned* __restrict__ Qd, unsigned* __restrict__ KVd,
                       int N)
{
    __shared__ unsigned short hs[64 * 136];

    if ((int)blockIdx.x < AB) {
        // ---- append phase -----------------------------------------------
        int t = (blockIdx.x * 256 + threadIdx.x) * 4;
        if (t + 3 < E) {
            int4 d4 = *(const int4*)(dst + t);
            int4 s4 = *(const int4*)(src + t);
            int sl0 = atomicAdd(&cnt[d4.x], 1);
            int sl1 = atomicAdd(&cnt[d4.y], 1);
            int sl2 = atomicAdd(&cnt[d4.z], 1);
            int sl3 = atomicAdd(&cnt[d4.w], 1);
            if (sl0 < CAP) srcsF[(size_t)d4.x * CAP + sl0] = (unsigned short)s4.x;
            if (sl1 < CAP) srcsF[(size_t)d4.y * CAP + sl1] = (unsigned short)s4.y;
            if (sl2 < CAP) srcsF[(size_t)d4.z * CAP + sl2] = (unsigned short)s4.z;
            if (sl3 < CAP) srcsF[(size_t)d4.w * CAP + sl3] = (unsigned short)s4.w;
        } else {
            for (int e = t; e < E; ++e) {
                int d    = dst[e];
                int slot = atomicAdd(&cnt[d], 1);
                if (slot < CAP) srcsF[(size_t)d * CAP + slot] = (unsigned short)src[e];
            }
        }
        return;
    }

    // ---- qkv phase ------------------------------------------------------
    const int tid = threadIdx.x;
    const int n0  = ((int)blockIdx.x - AB) * 64;

    #pragma unroll
    for (int i = 0; i < 4; ++i) {
        int lin  = i * 256 + tid;          // 0..1023
        int node = lin >> 4;               // 0..63
        int k0   = (lin & 15) * 8;         // 0..120
        int gn   = n0 + node;
        float4 a0, a1;
        if (gn < N) {
            a0 = *(const float4*)(h + (size_t)gn * DIM + k0);
            a1 = *(const float4*)(h + (size_t)gn * DIM + k0 + 4);
        } else {
            a0 = make_float4(0.f, 0.f, 0.f, 0.f);
            a1 = a0;
        }
        uint4 p = make_uint4(bf16pack2(a0.x, a0.y), bf16pack2(a0.z, a0.w),
                             bf16pack2(a1.x, a1.y), bf16pack2(a1.z, a1.w));
        *(uint4*)(hs + node * 136 + k0) = p;
    }
    __syncthreads();

    const int wave   = tid >> 6;
    const int l      = tid & 63;
    const int lane16 = l & 15;
    const int quad   = l >> 4;
    const int wc0    = wave * 96;

    // per-ct source array + local column (16-col blocks never straddle
    // the 128-col boundaries since wc0 = wave*96 and ct*16 steps by 16)
    const float* Wm[6]; const float* bm[6]; int cb[6];
    #pragma unroll
    for (int ct = 0; ct < 6; ++ct) {
        int col0 = wc0 + ct * 16;
        if (col0 < 128)      { Wm[ct] = WQ; bm[ct] = bQ; cb[ct] = col0; }
        else if (col0 < 256) { Wm[ct] = WK; bm[ct] = bK; cb[ct] = col0 - 128; }
        else                 { Wm[ct] = WV; bm[ct] = bV; cb[ct] = col0 - 256; }
    }

    f32x4 acc[6][4];
    #pragma unroll
    for (int ct = 0; ct < 6; ++ct) {
        float4 bv = *(const float4*)(bm[ct] + cb[ct] + quad * 4);
        #pragma unroll
        for (int rt = 0; rt < 4; ++rt)
            acc[ct][rt] = (f32x4){bv.x, bv.y, bv.z, bv.w};
    }

    #pragma unroll
    for (int ks = 0; ks < 4; ++ks) {
        const int kb = ks * 32 + quad * 8;       // fragment k-base
        bf16x8 a[6], b[4];
        #pragma unroll
        for (int ct = 0; ct < 6; ++ct) {
            const float* wp = Wm[ct] + (size_t)kb * DIM + cb[ct] + lane16;
            float w0 = wp[0 * DIM], w1 = wp[1 * DIM], w2 = wp[2 * DIM], w3 = wp[3 * DIM];
            float w4 = wp[4 * DIM], w5 = wp[5 * DIM], w6 = wp[6 * DIM], w7 = wp[7 * DIM];
            ui32x4 pk = { bf16pack2(w0, w1), bf16pack2(w2, w3),
                          bf16pack2(w4, w5), bf16pack2(w6, w7) };
            a[ct] = __builtin_bit_cast(bf16x8, pk);
        }
        #pragma unroll
        for (int rt = 0; rt < 4; ++rt)
            b[rt] = *(const bf16x8*)(hs + (rt * 16 + lane16) * 136 + ks * 32 + quad * 8);
        #pragma unroll
        for (int ct = 0; ct < 6; ++ct)
            #pragma unroll
            for (int rt = 0; rt < 4; ++rt)
                acc[ct][rt] = __builtin_amdgcn_mfma_f32_16x16x32_bf16(
                    a[ct], b[rt], acc[ct][rt], 0, 0, 0);
    }

    #pragma unroll
    for (int ct = 0; ct < 6; ++ct) {
        const int col = wc0 + ct * 16 + quad * 4;   // multiple of 4
        #pragma unroll
        for (int rt = 0; rt < 4; ++rt) {
            int gn = n0 + rt * 16 + lane16;
            if (gn >= N) continue;
            f32x4 v = acc[ct][rt];
            uint2 pr = make_uint2(bf16pack2(v[0], v[1]), bf16pack2(v[2], v[3]));
            if (col < 128) {
                *(uint2*)(Qd + (size_t)gn * 64 + (col >> 1)) = pr;
            } else if (col < 256) {
                int c = col - 128;
                *(uint2*)(KVd + (size_t)gn * 128 + ((c >> 3) * 8) + ((c & 4) >> 1)) = pr;
            } else {
                int c = col - 256;
                *(uint2*)(KVd + (size_t)gn * 128 + ((c >> 3) * 8) + 4 + ((c & 4) >> 1)) = pr;
            }
        }
    }
}

// ---------------------------------------------------------------------------
// Aggregate: EXACT round-2 v2 (61.4-62.0us measured; best of 10 structures).
// Persistent grid-stride waves + cross-node meta prefetch. Wave = one dst
// node, 4 edge slots, 16 lanes/edge (c = l&15 -> dims c*8..c*8+7).
// ---------------------------------------------------------------------------
__device__ __forceinline__ void agg_chunk16(
    const unsigned* __restrict__ KVd, int eg, int deg, int slot, int c,
    const int* raw,
    float q0, float q1, float q2, float q3,
    float q4, float q5, float q6, float q7,
    float acc[8], float& zs)
{
    bool val[4];
    const uint4* p[4];
    #pragma unroll
    for (int j = 0; j < 4; ++j) {
        int ee = eg + j * 4 + slot;
        val[j] = ee < deg;
        int s  = val[j] ? raw[j] : 0;
        p[j]   = (const uint4*)(KVd + (size_t)s * 128 + c * 8);
    }
    uint4 K[4], V[4];
    #pragma unroll
    for (int j = 0; j < 4; ++j) { K[j] = p[j][0]; V[j] = p[j][1]; }

    float d[4];
    #pragma unroll
    for (int j = 0; j < 4; ++j)
        d[j] = bf16lo(K[j].x) * q0 + bf16hi(K[j].x) * q1
             + bf16lo(K[j].y) * q2 + bf16hi(K[j].y) * q3
             + bf16lo(K[j].z) * q4 + bf16hi(K[j].z) * q5
             + bf16lo(K[j].w) * q6 + bf16hi(K[j].w) * q7;
    #pragma unroll
    for (int j = 0; j < 4; ++j) d[j] += __shfl_xor(d[j], 1);

    #pragma unroll
    for (int j = 0; j < 4; ++j) {
        float pc = fminf(fmaxf(d[j] * 0.25f, -5.0f), 5.0f);
        float w  = val[j] ? __expf(pc) : 0.0f;
        zs += w;
        acc[0] += w * bf16lo(V[j].x); acc[1] += w * bf16hi(V[j].x);
        acc[2] += w * bf16lo(V[j].y); acc[3] += w * bf16hi(V[j].y);
        acc[4] += w * bf16lo(V[j].z); acc[5] += w * bf16hi(V[j].z);
        acc[6] += w * bf16lo(V[j].w); acc[7] += w * bf16hi(V[j].w);
    }
}

__global__ __launch_bounds__(256, 4)
void aggregate_kernel(const int* __restrict__ cnt,
                      const unsigned short* __restrict__ srcsF,
                      const unsigned* __restrict__ Qd, const unsigned* __restrict__ KVd,
                      float* __restrict__ out, int N)
{
    const int l      = threadIdx.x & 63;
    const int slot   = l >> 4;
    const int c      = l & 15;
    const int stride = gridDim.x * 4;

    int node = blockIdx.x * 4 + (threadIdx.x >> 6);
    if (node >= N) return;

    // prime the pipeline: current node's deg, Q row, first 32 bucket slots
    int   deg = cnt[node];
    uint4 qd  = *(const uint4*)(Qd + (size_t)node * 64 + c * 4);
    int   pb[8];
    {
        const unsigned short* b = srcsF + (size_t)node * CAP;
        #pragma unroll
        for (int j = 0; j < 8; ++j)
            pb[j] = b[((j >> 2) << 4) + ((j & 3) << 2) + slot];   // ee 0..31
    }

    for (;;) {
        const int  nnode   = node + stride;
        const bool hasNext = nnode < N;

        // ---- prefetch next node (independent loads, hide under compute) --
        int ndeg = 0; uint4 nqd = make_uint4(0u, 0u, 0u, 0u); int npb[8];
        #pragma unroll
        for (int j = 0; j < 8; ++j) npb[j] = 0;
        if (hasNext) {
            ndeg = cnt[nnode];
            nqd  = *(const uint4*)(Qd + (size_t)nnode * 64 + c * 4);
            const unsigned short* b = srcsF + (size_t)nnode * CAP;
            #pragma unroll
            for (int j = 0; j < 8; ++j)
                npb[j] = b[((j >> 2) << 4) + ((j & 3) << 2) + slot];
        }

        // ---- process current node ---------------------------------------
        int degc = deg > CAP ? CAP : deg;
        const float q0 = bf16lo(qd.x), q1 = bf16hi(qd.x);
        const float q2 = bf16lo(qd.y), q3 = bf16hi(qd.y);
        const float q4 = bf16lo(qd.z), q5 = bf16hi(qd.z);
        const float q6 = bf16lo(qd.w), q7 = bf16hi(qd.w);

        float acc[8] = {0.f, 0.f, 0.f, 0.f, 0.f, 0.f, 0.f, 0.f};
        float zs = 0.f;

        if (degc > 0)
            agg_chunk16(KVd, 0, degc, slot, c, pb,
                        q0, q1, q2, q3, q4, q5, q6, q7, acc, zs);
        if (degc > 16)
            agg_chunk16(KVd, 16, degc, slot, c, pb + 4,
                        q0, q1, q2, q3, q4, q5, q6, q7, acc, zs);
        for (int eg = 32; eg < degc; eg += 16) {       // rare tail (deg > 32)
            int raw[4];
            const unsigned short* b = srcsF + (size_t)node * CAP;
            #pragma unroll
            for (int j = 0; j < 4; ++j) {
                int ee = eg + j * 4 + slot;
                raw[j] = b[ee < degc ? ee : 0];
            }
            agg_chunk16(KVd, eg, degc, slot, c, raw,
                        q0, q1, q2, q3, q4, q5, q6, q7, acc, zs);
        }

        // ---- cross-slot reduce (slots live in lane bits 4-5) ------------
        #pragma unroll
        for (int j = 0; j < 8; ++j) {
            acc[j] += __shfl_xor(acc[j], 16);
            acc[j] += __shfl_xor(acc[j], 32);
        }
        zs += __shfl_xor(zs, 16);
        zs += __shfl_xor(zs, 32);

        if (slot == 0) {
            float inv = (zs > 0.0f) ? (1.0f / zs) : 0.0f;
            *(float4*)(out + (size_t)node * DIM + c * 8) =
                make_float4(acc[0] * inv, acc[1] * inv, acc[2] * inv, acc[3] * inv);
            *(float4*)(out + (size_t)node * DIM + c * 8 + 4) =
                make_float4(acc[4] * inv, acc[5] * inv, acc[6] * inv, acc[7] * inv);
        }

        if (!hasNext) break;
        node = nnode; deg = ndeg; qd = nqd;
        #pragma unroll
        for (int j = 0; j < 8; ++j) pb[j] = npb[j];
    }
}

// ---------------------------------------------------------------------------
extern "C" void kernel_launch(void* const* d_in, const int* in_sizes, int n_in,
                              void* d_out, int out_size, void* d_ws, size_t ws_size,
                              hipStream_t stream) {
    const float* h   = (const float*)d_in[0];
    const int*   src = (const int*)  d_in[1];
    const int*   dst = (const int*)  d_in[2];
    const float* WQ  = (const float*)d_in[3];
    const float* bQ  = (const float*)d_in[4];
    const float* WK  = (const float*)d_in[5];
    const float* bK  = (const float*)d_in[6];
    const float* WV  = (const float*)d_in[7];
    const float* bV  = (const float*)d_in[8];
    float* out = (float*)d_out;

    const int N  = in_sizes[0] / DIM;
    const int E  = in_sizes[1];
    const int AB = (E / 4 + 255) / 256;        // append blocks (4 edges/thread)
    const int QB = (N + 63) / 64;              // qkv blocks

    // Workspace: Qd (12.8MB) | KVd (25.6MB) | cnt (200KB) | srcsF (6.4MB)
    char* w = (char*)d_ws;
    unsigned*       Qd    = (unsigned*)w;       w += (size_t)N * 64  * sizeof(unsigned);
    unsigned*       KVd   = (unsigned*)w;       w += (size_t)N * 128 * sizeof(unsigned);
    int*            cnt   = (int*)w;            w += (size_t)N * sizeof(int);
    unsigned short* srcsF = (unsigned short*)w;

    hipMemsetAsync(cnt, 0, (size_t)N * sizeof(int), stream);
    append_qkv_kernel<<<AB + QB, 256, 0, stream>>>(src, dst, cnt, srcsF, E, AB,
                                                   h, WQ, bQ, WK, bK, WV, bV,
                                                   Qd, KVd, N);
    aggregate_kernel<<<2048, 256, 0, stream>>>(cnt, srcsF, Qd, KVd, out, N);
}

// Round 12
// 213.813 us; speedup vs baseline: 1.0761x; 1.0099x over previous
//
#include <hip/hip_runtime.h>
#include <math.h>

// Problem constants: IN_DIM=128, HEADS=8, HEAD_DIM=16, HEADS*HEAD_DIM=128.
#define DIM 128
#define N_HEADS 8
#define HD 16
#define CAP 64   // bucket capacity (deg ~Poisson(16); P(>64)~3e-22)

typedef __attribute__((ext_vector_type(8))) short bf16x8;   // MFMA A/B frag (4 VGPRs)
typedef __attribute__((ext_vector_type(4))) float f32x4;    // MFMA C/D frag
typedef __attribute__((ext_vector_type(4))) unsigned ui32x4;

// ---------------------------------------------------------------------------
// ROUND-12: interleaved block roles in the fused aq kernel.
// R1/R5/R11 evidence: contiguous role ranges give ZERO overlap -- the first
// phase's 782 blocks all fit co-resident (4-5 blocks/CU x 256 CU), so the
// machine drains phase 1 fully before phase 2 starts (fused == sum of parts).
// Fix: role = bid parity (AB == QB == 782). Every CU gets a mix of append
// waves (latency-bound on L3 atomics) and qkv waves (MFMA/LDS/HBM) from t=0;
// append's stalls hide under qkv's compute. Same work, same traffic.
// Everything else verbatim R11 (216us best: memset-init + direct-W qkv +
// R2-v2 aggregate).
// ---------------------------------------------------------------------------

__device__ __forceinline__ unsigned bf16pack2(float a, float b) {
    unsigned ua = __builtin_bit_cast(unsigned, a);
    unsigned ub = __builtin_bit_cast(unsigned, b);
    ua = (ua + 0x7FFFu + ((ua >> 16) & 1u)) >> 16;
    ub = (ub + 0x7FFFu + ((ub >> 16) & 1u)) >> 16;
    return ua | (ub << 16);
}
__device__ __forceinline__ float bf16lo(unsigned p) {
    return __builtin_bit_cast(float, p << 16);
}
__device__ __forceinline__ float bf16hi(unsigned p) {
    return __builtin_bit_cast(float, p & 0xFFFF0000u);
}

// ---------------------------------------------------------------------------
// Fused append + qkv, INTERLEAVED roles.
// append: 4 edges/thread, int4 edge loads, ushort bucket entries (N < 65536).
// qkv: A-fragments packed on the fly from f32 W (L2-resident, 8 strided
//   dword loads + 4 packs per fragment).
// Qd layout (dwords; row n = 64 dwords = 256 B): dword j = Q dims 2j,2j+1.
// KV chunk layout (dwords; row n = 128 dwords = 512 B):
//   chunk c in [0,16): dwords [8c..8c+3] = K dims 8c..8c+7,
//                      dwords [8c+4..8c+7] = V dims 8c..8c+7.
// ---------------------------------------------------------------------------
__global__ __launch_bounds__(256)
void append_qkv_kernel(const int* __restrict__ src, const int* __restrict__ dst,
                       int* __restrict__ cnt, unsigned short* __restrict__ srcsF,
                       int E, int AB, int QB,
                       const float* __restrict__ h,
                       const float* __restrict__ WQ, const float* __restrict__ bQ,
                       const float* __restrict__ WK, const float* __restrict__ bK,
                       const float* __restrict__ WV, const float* __restrict__ bV,
                       unsigned* __restrict__ Qd, unsigned* __restrict__ KVd,
                       int N)
{
    __shared__ unsigned short hs[64 * 136];

    // ---- interleaved role mapping: even bid -> qkv, odd bid -> append ----
    const int bid = (int)blockIdx.x;
    const int M   = 2 * (AB < QB ? AB : QB);
    bool isAppend; int widx;
    if (bid < M) { isAppend = (bid & 1); widx = bid >> 1; }
    else         { isAppend = (AB > QB); widx = bid - M + (AB < QB ? AB : QB); }

    if (isAppend) {
        // ---- append phase -----------------------------------------------
        int t = (widx * 256 + (int)threadIdx.x) * 4;
        if (t + 3 < E) {
            int4 d4 = *(const int4*)(dst + t);
            int4 s4 = *(const int4*)(src + t);
            int sl0 = atomicAdd(&cnt[d4.x], 1);
            int sl1 = atomicAdd(&cnt[d4.y], 1);
            int sl2 = atomicAdd(&cnt[d4.z], 1);
            int sl3 = atomicAdd(&cnt[d4.w], 1);
            if (sl0 < CAP) srcsF[(size_t)d4.x * CAP + sl0] = (unsigned short)s4.x;
            if (sl1 < CAP) srcsF[(size_t)d4.y * CAP + sl1] = (unsigned short)s4.y;
            if (sl2 < CAP) srcsF[(size_t)d4.z * CAP + sl2] = (unsigned short)s4.z;
            if (sl3 < CAP) srcsF[(size_t)d4.w * CAP + sl3] = (unsigned short)s4.w;
        } else if (t < E) {
            for (int e = t; e < E; ++e) {
                int d    = dst[e];
                int slot = atomicAdd(&cnt[d], 1);
                if (slot < CAP) srcsF[(size_t)d * CAP + slot] = (unsigned short)src[e];
            }
        }
        return;
    }

    // ---- qkv phase ------------------------------------------------------
    const int tid = threadIdx.x;
    const int n0  = widx * 64;

    #pragma unroll
    for (int i = 0; i < 4; ++i) {
        int lin  = i * 256 + tid;          // 0..1023
        int node = lin >> 4;               // 0..63
        int k0   = (lin & 15) * 8;         // 0..120
        int gn   = n0 + node;
        float4 a0, a1;
        if (gn < N) {
            a0 = *(const float4*)(h + (size_t)gn * DIM + k0);
            a1 = *(const float4*)(h + (size_t)gn * DIM + k0 + 4);
        } else {
            a0 = make_float4(0.f, 0.f, 0.f, 0.f);
            a1 = a0;
        }
        uint4 p = make_uint4(bf16pack2(a0.x, a0.y), bf16pack2(a0.z, a0.w),
                             bf16pack2(a1.x, a1.y), bf16pack2(a1.z, a1.w));
        *(uint4*)(hs + node * 136 + k0) = p;
    }
    __syncthreads();

    const int wave   = tid >> 6;
    const int l      = tid & 63;
    const int lane16 = l & 15;
    const int quad   = l >> 4;
    const int wc0    = wave * 96;

    // per-ct source array + local column (16-col blocks never straddle
    // the 128-col boundaries since wc0 = wave*96 and ct*16 steps by 16)
    const float* Wm[6]; const float* bm[6]; int cb[6];
    #pragma unroll
    for (int ct = 0; ct < 6; ++ct) {
        int col0 = wc0 + ct * 16;
        if (col0 < 128)      { Wm[ct] = WQ; bm[ct] = bQ; cb[ct] = col0; }
        else if (col0 < 256) { Wm[ct] = WK; bm[ct] = bK; cb[ct] = col0 - 128; }
        else                 { Wm[ct] = WV; bm[ct] = bV; cb[ct] = col0 - 256; }
    }

    f32x4 acc[6][4];
    #pragma unroll
    for (int ct = 0; ct < 6; ++ct) {
        float4 bv = *(const float4*)(bm[ct] + cb[ct] + quad * 4);
        #pragma unroll
        for (int rt = 0; rt < 4; ++rt)
            acc[ct][rt] = (f32x4){bv.x, bv.y, bv.z, bv.w};
    }

    #pragma unroll
    for (int ks = 0; ks < 4; ++ks) {
        const int kb = ks * 32 + quad * 8;       // fragment k-base
        bf16x8 a[6], b[4];
        #pragma unroll
        for (int ct = 0; ct < 6; ++ct) {
            const float* wp = Wm[ct] + (size_t)kb * DIM + cb[ct] + lane16;
            float w0 = wp[0 * DIM], w1 = wp[1 * DIM], w2 = wp[2 * DIM], w3 = wp[3 * DIM];
            float w4 = wp[4 * DIM], w5 = wp[5 * DIM], w6 = wp[6 * DIM], w7 = wp[7 * DIM];
            ui32x4 pk = { bf16pack2(w0, w1), bf16pack2(w2, w3),
                          bf16pack2(w4, w5), bf16pack2(w6, w7) };
            a[ct] = __builtin_bit_cast(bf16x8, pk);
        }
        #pragma unroll
        for (int rt = 0; rt < 4; ++rt)
            b[rt] = *(const bf16x8*)(hs + (rt * 16 + lane16) * 136 + ks * 32 + quad * 8);
        #pragma unroll
        for (int ct = 0; ct < 6; ++ct)
            #pragma unroll
            for (int rt = 0; rt < 4; ++rt)
                acc[ct][rt] = __builtin_amdgcn_mfma_f32_16x16x32_bf16(
                    a[ct], b[rt], acc[ct][rt], 0, 0, 0);
    }

    #pragma unroll
    for (int ct = 0; ct < 6; ++ct) {
        const int col = wc0 + ct * 16 + quad * 4;   // multiple of 4
        #pragma unroll
        for (int rt = 0; rt < 4; ++rt) {
            int gn = n0 + rt * 16 + lane16;
            if (gn >= N) continue;
            f32x4 v = acc[ct][rt];
            uint2 pr = make_uint2(bf16pack2(v[0], v[1]), bf16pack2(v[2], v[3]));
            if (col < 128) {
                *(uint2*)(Qd + (size_t)gn * 64 + (col >> 1)) = pr;
            } else if (col < 256) {
                int c = col - 128;
                *(uint2*)(KVd + (size_t)gn * 128 + ((c >> 3) * 8) + ((c & 4) >> 1)) = pr;
            } else {
                int c = col - 256;
                *(uint2*)(KVd + (size_t)gn * 128 + ((c >> 3) * 8) + 4 + ((c & 4) >> 1)) = pr;
            }
        }
    }
}

// ---------------------------------------------------------------------------
// Aggregate: EXACT round-2 v2 (61.4-65us measured; best of 10 structures).
// Persistent grid-stride waves + cross-node meta prefetch. Wave = one dst
// node, 4 edge slots, 16 lanes/edge (c = l&15 -> dims c*8..c*8+7).
// ---------------------------------------------------------------------------
__device__ __forceinline__ void agg_chunk16(
    const unsigned* __restrict__ KVd, int eg, int deg, int slot, int c,
    const int* raw,
    float q0, float q1, float q2, float q3,
    float q4, float q5, float q6, float q7,
    float acc[8], float& zs)
{
    bool val[4];
    const uint4* p[4];
    #pragma unroll
    for (int j = 0; j < 4; ++j) {
        int ee = eg + j * 4 + slot;
        val[j] = ee < deg;
        int s  = val[j] ? raw[j] : 0;
        p[j]   = (const uint4*)(KVd + (size_t)s * 128 + c * 8);
    }
    uint4 K[4], V[4];
    #pragma unroll
    for (int j = 0; j < 4; ++j) { K[j] = p[j][0]; V[j] = p[j][1]; }

    float d[4];
    #pragma unroll
    for (int j = 0; j < 4; ++j)
        d[j] = bf16lo(K[j].x) * q0 + bf16hi(K[j].x) * q1
             + bf16lo(K[j].y) * q2 + bf16hi(K[j].y) * q3
             + bf16lo(K[j].z) * q4 + bf16hi(K[j].z) * q5
             + bf16lo(K[j].w) * q6 + bf16hi(K[j].w) * q7;
    #pragma unroll
    for (int j = 0; j < 4; ++j) d[j] += __shfl_xor(d[j], 1);

    #pragma unroll
    for (int j = 0; j < 4; ++j) {
        float pc = fminf(fmaxf(d[j] * 0.25f, -5.0f), 5.0f);
        float w  = val[j] ? __expf(pc) : 0.0f;
        zs += w;
        acc[0] += w * bf16lo(V[j].x); acc[1] += w * bf16hi(V[j].x);
        acc[2] += w * bf16lo(V[j].y); acc[3] += w * bf16hi(V[j].y);
        acc[4] += w * bf16lo(V[j].z); acc[5] += w * bf16hi(V[j].z);
        acc[6] += w * bf16lo(V[j].w); acc[7] += w * bf16hi(V[j].w);
    }
}

__global__ __launch_bounds__(256, 4)
void aggregate_kernel(const int* __restrict__ cnt,
                      const unsigned short* __restrict__ srcsF,
                      const unsigned* __restrict__ Qd, const unsigned* __restrict__ KVd,
                      float* __restrict__ out, int N)
{
    const int l      = threadIdx.x & 63;
    const int slot   = l >> 4;
    const int c      = l & 15;
    const int stride = gridDim.x * 4;

    int node = blockIdx.x * 4 + (threadIdx.x >> 6);
    if (node >= N) return;

    // prime the pipeline: current node's deg, Q row, first 32 bucket slots
    int   deg = cnt[node];
    uint4 qd  = *(const uint4*)(Qd + (size_t)node * 64 + c * 4);
    int   pb[8];
    {
        const unsigned short* b = srcsF + (size_t)node * CAP;
        #pragma unroll
        for (int j = 0; j < 8; ++j)
            pb[j] = b[((j >> 2) << 4) + ((j & 3) << 2) + slot];   // ee 0..31
    }

    for (;;) {
        const int  nnode   = node + stride;
        const bool hasNext = nnode < N;

        // ---- prefetch next node (independent loads, hide under compute) --
        int ndeg = 0; uint4 nqd = make_uint4(0u, 0u, 0u, 0u); int npb[8];
        #pragma unroll
        for (int j = 0; j < 8; ++j) npb[j] = 0;
        if (hasNext) {
            ndeg = cnt[nnode];
            nqd  = *(const uint4*)(Qd + (size_t)nnode * 64 + c * 4);
            const unsigned short* b = srcsF + (size_t)nnode * CAP;
            #pragma unroll
            for (int j = 0; j < 8; ++j)
                npb[j] = b[((j >> 2) << 4) + ((j & 3) << 2) + slot];
        }

        // ---- process current node ---------------------------------------
        int degc = deg > CAP ? CAP : deg;
        const float q0 = bf16lo(qd.x), q1 = bf16hi(qd.x);
        const float q2 = bf16lo(qd.y), q3 = bf16hi(qd.y);
        const float q4 = bf16lo(qd.z), q5 = bf16hi(qd.z);
        const float q6 = bf16lo(qd.w), q7 = bf16hi(qd.w);

        float acc[8] = {0.f, 0.f, 0.f, 0.f, 0.f, 0.f, 0.f, 0.f};
        float zs = 0.f;

        if (degc > 0)
            agg_chunk16(KVd, 0, degc, slot, c, pb,
                        q0, q1, q2, q3, q4, q5, q6, q7, acc, zs);
        if (degc > 16)
            agg_chunk16(KVd, 16, degc, slot, c, pb + 4,
                        q0, q1, q2, q3, q4, q5, q6, q7, acc, zs);
        for (int eg = 32; eg < degc; eg += 16) {       // rare tail (deg > 32)
            int raw[4];
            const unsigned short* b = srcsF + (size_t)node * CAP;
            #pragma unroll
            for (int j = 0; j < 4; ++j) {
                int ee = eg + j * 4 + slot;
                raw[j] = b[ee < degc ? ee : 0];
            }
            agg_chunk16(KVd, eg, degc, slot, c, raw,
                        q0, q1, q2, q3, q4, q5, q6, q7, acc, zs);
        }

        // ---- cross-slot reduce (slots live in lane bits 4-5) ------------
        #pragma unroll
        for (int j = 0; j < 8; ++j) {
            acc[j] += __shfl_xor(acc[j], 16);
            acc[j] += __shfl_xor(acc[j], 32);
        }
        zs += __shfl_xor(zs, 16);
        zs += __shfl_xor(zs, 32);

        if (slot == 0) {
            float inv = (zs > 0.0f) ? (1.0f / zs) : 0.0f;
            *(float4*)(out + (size_t)node * DIM + c * 8) =
                make_float4(acc[0] * inv, acc[1] * inv, acc[2] * inv, acc[3] * inv);
            *(float4*)(out + (size_t)node * DIM + c * 8 + 4) =
                make_float4(acc[4] * inv, acc[5] * inv, acc[6] * inv, acc[7] * inv);
        }

        if (!hasNext) break;
        node = nnode; deg = ndeg; qd = nqd;
        #pragma unroll
        for (int j = 0; j < 8; ++j) pb[j] = npb[j];
    }
}

// ---------------------------------------------------------------------------
extern "C" void kernel_launch(void* const* d_in, const int* in_sizes, int n_in,
                              void* d_out, int out_size, void* d_ws, size_t ws_size,
                              hipStream_t stream) {
    const float* h   = (const float*)d_in[0];
    const int*   src = (const int*)  d_in[1];
    const int*   dst = (const int*)  d_in[2];
    const float* WQ  = (const float*)d_in[3];
    const float* bQ  = (const float*)d_in[4];
    const float* WK  = (const float*)d_in[5];
    const float* bK  = (const float*)d_in[6];
    const float* WV  = (const float*)d_in[7];
    const float* bV  = (const float*)d_in[8];
    float* out = (float*)d_out;

    const int N  = in_sizes[0] / DIM;
    const int E  = in_sizes[1];
    const int AB = (E / 4 + 255) / 256;        // append blocks (4 edges/thread)
    const int QB = (N + 63) / 64;              // qkv blocks

    // Workspace: Qd (12.8MB) | KVd (25.6MB) | cnt (200KB) | srcsF (6.4MB)
    char* w = (char*)d_ws;
    unsigned*       Qd    = (unsigned*)w;       w += (size_t)N * 64  * sizeof(unsigned);
    unsigned*       KVd   = (unsigned*)w;       w += (size_t)N * 128 * sizeof(unsigned);
    int*            cnt   = (int*)w;            w += (size_t)N * sizeof(int);
    unsigned short* srcsF = (unsigned short*)w;

    hipMemsetAsync(cnt, 0, (size_t)N * sizeof(int), stream);
    append_qkv_kernel<<<AB + QB, 256, 0, stream>>>(src, dst, cnt, srcsF, E, AB, QB,
                                                   h, WQ, bQ, WK, bK, WV, bV,
                                                   Qd, KVd, N);
    aggregate_kernel<<<2048, 256, 0, stream>>>(cnt, srcsF, Qd, KVd, out, N);
}